// Round 6
// baseline (199.656 us; speedup 1.0000x reference)
//
#include <hip/hip_runtime.h>

#define BB 16
#define CIN 512
#define LLN 2048
#define EPSV 1e-5f

typedef __attribute__((ext_vector_type(8))) short bf16x8s;
typedef __attribute__((ext_vector_type(4))) float f32x4;

__device__ __forceinline__ unsigned short f2bf(float f) {
    union { float f; unsigned int i; } c; c.f = f;
    unsigned int x = c.i;
    unsigned int lsb = (x >> 16) & 1;
    x += 0x7fff + lsb;            // RNE
    return (unsigned short)(x >> 16);
}
__device__ __forceinline__ unsigned int pack2bf(float a, float b) {
    return (unsigned int)f2bf(a) | ((unsigned int)f2bf(b) << 16);
}
__device__ __forceinline__ float bf2f(unsigned short u) {
    union { unsigned int i; float f; } c; c.i = ((unsigned int)u) << 16; return c.f;
}
__device__ __forceinline__ float bflo(unsigned int w) {
    union { unsigned int i; float f; } c; c.i = w << 16; return c.f;
}
__device__ __forceinline__ float bfhi(unsigned int w) {
    union { unsigned int i; float f; } c; c.i = w & 0xffff0000u; return c.f;
}

// async global->LDS, 16B per lane, LDS dest = wave-uniform base + lane*16
__device__ __forceinline__ void g2l16(const void* g, void* l) {
    typedef const __attribute__((address_space(1))) unsigned int GU;
    typedef __attribute__((address_space(3))) unsigned int LU;
    __builtin_amdgcn_global_load_lds((GU*)g, (LU*)l, 16, 0, 0);
}

// ---------------- Kernel 0: prep (x repack + weight repack, one dispatch) ----
// xpk: [b][chunk 16][rp 2050][32 u16], rp = n+1 (rows 0,2049 zero halo); logical
// ci-group g (8 ci) of row rp is stored at 16B slot (g ^ ((rp>>1)&3)).
// Wpk: [cot 4][chunk 16] images of [t 3][cf 4][lane 64][e 8] bf16 (6144 u16):
//   lane holds W[co=cot*64+cf*16+(lane&15)][ci0+(lane>>4)*8+e][t] (frag-contig,
//   so conv can load weights per-lane straight into VGPRs).
#define WIMG_U16 6144

__global__ __launch_bounds__(256) void prep_all(
    const float* __restrict__ x,
    const float* __restrict__ Wq, const float* __restrict__ Wk,
    const float* __restrict__ Wv,
    unsigned short* __restrict__ xpk, unsigned short* __restrict__ Wpk)
{
    const int tid = threadIdx.x;
    if (blockIdx.z < 16) {
        // ---- x repack: block = (n-tile 256, ci-chunk, b), 2048 blocks ----
        __shared__ __align__(16) unsigned int xs[256 * 16];   // 16 KB: [nl][16 u32]
        const int nt = blockIdx.x;   // 0..7
        const int c  = blockIdx.y;   // 0..15
        const int b  = blockIdx.z;   // 0..15
        const int n0 = nt * 256;
        const int p  = tid >> 4;         // ci pair 0..15
        const int ns = (tid & 15) * 4;   // n_local base
        const int g = p >> 2, pi = p & 3;
        const float* x0 = x + ((size_t)b * CIN + (size_t)(c * 32 + 2 * p)) * LLN + n0;
#pragma unroll
        for (int j = 0; j < 4; j++) {
            int nl = ns + j * 64;
            float4 a = *(const float4*)&x0[nl];
            float4 bq = *(const float4*)&x0[LLN + nl];
            int rp = n0 + nl + 1;
            xs[(nl + 0) * 16 + (g ^ (((rp + 0) >> 1) & 3)) * 4 + pi] = pack2bf(a.x, bq.x);
            xs[(nl + 1) * 16 + (g ^ (((rp + 1) >> 1) & 3)) * 4 + pi] = pack2bf(a.y, bq.y);
            xs[(nl + 2) * 16 + (g ^ (((rp + 2) >> 1) & 3)) * 4 + pi] = pack2bf(a.z, bq.z);
            xs[(nl + 3) * 16 + (g ^ (((rp + 3) >> 1) & 3)) * 4 + pi] = pack2bf(a.w, bq.w);
        }
        __syncthreads();
        // coalesced copy-out: 16 KB contiguous (rows n0+1 .. n0+256)
        uint4* dst = (uint4*)(xpk + ((size_t)(b * 16 + c) * 2050 + n0 + 1) * 32);
        const uint4* srcl = (const uint4*)xs;
#pragma unroll
        for (int k = 0; k < 4; k++)
            dst[tid + k * 256] = srcl[tid + k * 256];
        // zero halo rows rp=0 and rp=2049
        if (nt == 0 && tid < 4)
            *(uint4*)(xpk + ((size_t)(b * 16 + c) * 2050) * 32 + tid * 8) = make_uint4(0, 0, 0, 0);
        if (nt == 7 && tid < 4)
            *(uint4*)(xpk + ((size_t)(b * 16 + c) * 2050 + 2049) * 32 + tid * 8) = make_uint4(0, 0, 0, 0);
    } else {
        // ---- weight repack: 128 blocks, half an image each ----
        const int wblk = blockIdx.y * 8 + blockIdx.x;   // 0..127
        const int img = wblk >> 1, half = wblk & 1;     // img = cot*16 + chunk
        const int cot = img >> 4, chunk = img & 15;
        const int ci0 = chunk * 32;
        for (int i = half * 3072 + tid; i < half * 3072 + 3072; i += 256) {
            int t = i >> 11, r = i & 2047;
            int cf = r >> 9, lane = (r >> 3) & 63, e = i & 7;
            int lm = lane & 15, kq = lane >> 4;
            int cop = cot * 64 + cf * 16 + lm;
            int cig = ci0 + kq * 8 + e;
            float val = 0.f;
            if (cop < 64)        val = Wq[((size_t)cop * 512 + cig) * 3 + t];
            else if (cop < 80)   val = Wk[((size_t)(cop - 64) * 512 + cig) * 3 + t];
            else if (cop < 208)  val = Wv[((size_t)(cop - 80) * 512 + cig) * 3 + t];
            Wpk[(size_t)img * WIMG_U16 + i] = f2bf(val);
        }
    }
}

// ---------------- Kernel 1: MFMA conv (q|k|v) + BN, double-buffered ----------
// Block: 64 co x 128 n, 4 waves (each 64co x 32n), 16 K-chunks of 32 ci.
// grid 1024 = 4 blocks/CU (16 waves/CU). x double-buffered in LDS (17 KB);
// weights loaded per-lane straight into VGPRs (Wpk is frag-contiguous, L2-hot).
// q,v stored bf16; k stored as exp(score-16) so softmax needs no max pass.
__global__ __launch_bounds__(256, 4) void conv_mfma(
    const unsigned short* __restrict__ xpk, const unsigned short* __restrict__ Wpk,
    const float* __restrict__ qg, const float* __restrict__ qb,
    const float* __restrict__ qm, const float* __restrict__ qv,
    const float* __restrict__ vg, const float* __restrict__ vb,
    const float* __restrict__ vm, const float* __restrict__ vvar,
    unsigned short* __restrict__ qb16, float* __restrict__ kbuf,
    unsigned short* __restrict__ vb16)
{
    __shared__ __align__(16) unsigned short xT[2][130 * 32];   // 2 x 8320 B
    __shared__ float sscale[64], sshift[64];

    const int tid = threadIdx.x;
    const int wave = tid >> 6, lane = tid & 63;
    const int kq = lane >> 4, lm = lane & 15;
    const int n0 = blockIdx.x * 128;     // 16 n-tiles
    const int cot = blockIdx.y;          // 0..3 (64 co each)
    const int b = blockIdx.z;

    const unsigned short* xpanel = xpk + ((size_t)b * 16 * 2050 + n0) * 32;
    const unsigned short* wlane  = Wpk + (size_t)cot * 16 * WIMG_U16 + (size_t)lane * 8;

#define STAGE_X(buf, chunk)                                                     \
    {                                                                           \
        const unsigned short* xsrc = xpanel + (size_t)(chunk) * 2050 * 32;      \
        for (int i = tid; i < 520; i += 256) g2l16(xsrc + (size_t)i * 8, &xT[buf][i * 8]); \
    }

    STAGE_X(0, 0)

    if (tid < 64) {                      // BN prep overlaps prologue loads
        int cop = cot * 64 + tid;
        float sc = 1.f, sh = 0.f;
        if (cop < 64) {
            float g = qg[cop], be = qb[cop], m = qm[cop], va = qv[cop];
            sc = g * rsqrtf(va + EPSV); sh = be - m * sc;
        } else if (cop >= 80 && cop < 208) {
            int cc = cop - 80;
            float g = vg[cc], be = vb[cc], m = vm[cc], va = vvar[cc];
            sc = g * rsqrtf(va + EPSV); sh = be - m * sc;
        }
        sscale[tid] = sc; sshift[tid] = sh;
    }

    f32x4 acc[4][2];
#pragma unroll
    for (int i = 0; i < 4; i++)
#pragma unroll
        for (int j = 0; j < 2; j++) acc[i][j] = (f32x4){0.f, 0.f, 0.f, 0.f};

    asm volatile("s_waitcnt vmcnt(0)" ::: "memory");
    __syncthreads();

    for (int chunk = 0; chunk < 16; chunk++) {
        const int cur = chunk & 1;
        // weights for THIS chunk -> VGPRs (issued before the x prefetch so the
        // first MFMA's vmcnt wait doesn't cover next-chunk staging)
        const unsigned short* wc = wlane + (size_t)chunk * WIMG_U16;
        bf16x8s aF[3][4];
#pragma unroll
        for (int t = 0; t < 3; t++)
#pragma unroll
            for (int cf = 0; cf < 4; cf++)
                aF[t][cf] = *(const bf16x8s*)&wc[(t * 4 + cf) * 512];

        if (chunk < 15) STAGE_X(cur ^ 1, chunk + 1)

#pragma unroll
        for (int t = 0; t < 3; t++) {
#pragma unroll
            for (int fn = 0; fn < 2; fn++) {
                int lr = wave * 32 + fn * 16 + lm + t;
                int grp = kq ^ ((lr >> 1) & 3);       // matches prep pre-swizzle
                bf16x8s bF = *(const bf16x8s*)&xT[cur][lr * 32 + grp * 8];
#pragma unroll
                for (int cf = 0; cf < 4; cf++)
                    acc[cf][fn] = __builtin_amdgcn_mfma_f32_16x16x32_bf16(
                        aF[t][cf], bF, acc[cf][fn], 0, 0, 0);
            }
        }
        asm volatile("s_waitcnt vmcnt(0)" ::: "memory");
        __syncthreads();
    }
#undef STAGE_X

    // epilogue: C layout col=lane&15 (n), row=(lane>>4)*4+reg (co)
#pragma unroll
    for (int cf = 0; cf < 4; cf++) {
#pragma unroll
        for (int fn = 0; fn < 2; fn++) {
#pragma unroll
            for (int r = 0; r < 4; r++) {
                int col = cf * 16 + kq * 4 + r;        // co_local 0..63
                int cop = cot * 64 + col;
                if (cop >= 208) continue;
                float val = acc[cf][fn][r] * sscale[col] + sshift[col];
                int nout = n0 + wave * 32 + fn * 16 + lm;
                if (cop < 64)
                    qb16[((size_t)b * 64 + cop) * LLN + nout] = f2bf(val);
                else if (cop < 80)
                    kbuf[((size_t)b * 16 + (cop - 64)) * LLN + nout] = __expf(val - 16.f);
                else
                    vb16[((size_t)b * 128 + (cop - 80)) * LLN + nout] = f2bf(val);
            }
        }
    }
}

// ---------------- Kernel 2: lambda_c from pre-exponentiated scores ----------
// kbuf already holds exp(score-16); softmax = ratio of sums, so a SINGLE pass:
// lambda_c[b][k][v] = (sum_n e[k][n]*v[v][n]) / (sum_n e[k][n]).
// block = (b, v-group-of-4); wave owns 4 k-rows. v read as bf16 x8.
__global__ __launch_bounds__(256) void lambdac_kernel(
    const float* __restrict__ kexp, const unsigned short* __restrict__ vb16,
    float* __restrict__ lcb)
{
    const int wave = threadIdx.x >> 6;
    const int lane = threadIdx.x & 63;
    const int b = blockIdx.x >> 5;
    const int vg = blockIdx.x & 31;
    const float* ps = kexp + ((size_t)b * 16 + wave * 4) * LLN;
    const unsigned short* pv = vb16 + ((size_t)b * 128 + vg * 4) * LLN;

    float sum[4] = {0.f, 0.f, 0.f, 0.f};
    float acc[4][4];
#pragma unroll
    for (int k = 0; k < 4; k++)
#pragma unroll
        for (int v = 0; v < 4; v++) acc[k][v] = 0.f;
#pragma unroll
    for (int j = 0; j < 4; j++) {
        int n = (j * 64 + lane) * 8;
        float e[4][8];
#pragma unroll
        for (int k = 0; k < 4; k++) {
            float4 a = *(const float4*)&ps[(size_t)k * LLN + n];
            float4 c = *(const float4*)&ps[(size_t)k * LLN + n + 4];
            e[k][0] = a.x; e[k][1] = a.y; e[k][2] = a.z; e[k][3] = a.w;
            e[k][4] = c.x; e[k][5] = c.y; e[k][6] = c.z; e[k][7] = c.w;
            sum[k] += a.x + a.y + a.z + a.w + c.x + c.y + c.z + c.w;
        }
#pragma unroll
        for (int v = 0; v < 4; v++) {
            uint4 w = *(const uint4*)&pv[(size_t)v * LLN + n];
            float vv[8] = {bflo(w.x), bfhi(w.x), bflo(w.y), bfhi(w.y),
                           bflo(w.z), bfhi(w.z), bflo(w.w), bfhi(w.w)};
#pragma unroll
            for (int k = 0; k < 4; k++) {
                float t = 0.f;
#pragma unroll
                for (int q = 0; q < 8; q++) t += e[k][q] * vv[q];
                acc[k][v] += t;
            }
        }
    }
#pragma unroll
    for (int k = 0; k < 4; k++) {
#pragma unroll
        for (int off = 32; off > 0; off >>= 1)
            sum[k] += __shfl_xor(sum[k], off, 64);
#pragma unroll
        for (int v = 0; v < 4; v++)
#pragma unroll
            for (int off = 32; off > 0; off >>= 1)
                acc[k][v] += __shfl_xor(acc[k][v], off, 64);
    }
    if (lane == 0) {
#pragma unroll
        for (int k = 0; k < 4; k++) {
            float inv = 1.f / sum[k];
#pragma unroll
            for (int v = 0; v < 4; v++)
                lcb[((size_t)b * 16 + wave * 4 + k) * 128 + vg * 4 + v] = acc[k][v] * inv;
        }
    }
}

// ---------------- Kernel 3: output, all 4 heads fused ----------------
// out[b][h*128+v][n] = sum_k q[b][h*16+k][n]*lc[b][k][v] + (sum_k q*emb[k])*v[b][v][n]
// block = (n-tile 64, b); wave = head. q,v read as bf16.
__global__ __launch_bounds__(256) void final_kernel(
    const unsigned short* __restrict__ qb16, const unsigned short* __restrict__ vb16,
    const float* __restrict__ lcb, const float* __restrict__ emb,
    float* __restrict__ out)
{
    __shared__ float lcsT[128][16];   // transposed: row v, 16 k contiguous
    __shared__ float es[16];
    const int tid = threadIdx.x;
    const int h = tid >> 6, nl = tid & 63;
    const int n0 = blockIdx.x * 64;   // 32 tiles
    const int b = blockIdx.y;

    for (int i = tid; i < 2048; i += 256)
        lcsT[i >> 4][i & 15] = lcb[(size_t)b * 2048 + (size_t)(i & 15) * 128 + (i >> 4)];
    if (tid < 16) es[tid] = emb[tid];
    __syncthreads();

    const int n = n0 + nl;
    const unsigned short* pq = qb16 + ((size_t)b * 64 + h * 16) * LLN + n;
    float4 q4[4];
#pragma unroll
    for (int kk = 0; kk < 4; kk++) {
        q4[kk].x = bf2f(pq[(size_t)(kk * 4 + 0) * LLN]);
        q4[kk].y = bf2f(pq[(size_t)(kk * 4 + 1) * LLN]);
        q4[kk].z = bf2f(pq[(size_t)(kk * 4 + 2) * LLN]);
        q4[kk].w = bf2f(pq[(size_t)(kk * 4 + 3) * LLN]);
    }
    float s = 0.f;
#pragma unroll
    for (int kk = 0; kk < 4; kk++)
        s += q4[kk].x * es[kk * 4] + q4[kk].y * es[kk * 4 + 1]
           + q4[kk].z * es[kk * 4 + 2] + q4[kk].w * es[kk * 4 + 3];

    const unsigned short* pv = vb16 + (size_t)b * 128 * LLN + n;
    float* po = out + ((size_t)b * 512 + h * 128) * LLN + n;
#pragma unroll 4
    for (int v = 0; v < 128; v++) {
        float4 c0 = *(const float4*)&lcsT[v][0];
        float4 c1 = *(const float4*)&lcsT[v][4];
        float4 c2 = *(const float4*)&lcsT[v][8];
        float4 c3 = *(const float4*)&lcsT[v][12];
        float lam = q4[0].x * c0.x + q4[0].y * c0.y + q4[0].z * c0.z + q4[0].w * c0.w
                  + q4[1].x * c1.x + q4[1].y * c1.y + q4[1].z * c1.z + q4[1].w * c1.w
                  + q4[2].x * c2.x + q4[2].y * c2.y + q4[2].z * c2.z + q4[2].w * c2.w
                  + q4[3].x * c3.x + q4[3].y * c3.y + q4[3].z * c3.z + q4[3].w * c3.w;
        float vvv = bf2f(pv[(size_t)v * LLN]);
        po[(size_t)v * LLN] = lam + s * vvv;
    }
}

extern "C" void kernel_launch(void* const* d_in, const int* in_sizes, int n_in,
                              void* d_out, int out_size, void* d_ws, size_t ws_size,
                              hipStream_t stream)
{
    const float* x   = (const float*)d_in[0];
    const float* Wq  = (const float*)d_in[1];
    const float* qg  = (const float*)d_in[2];
    const float* qb  = (const float*)d_in[3];
    const float* qm  = (const float*)d_in[4];
    const float* qv  = (const float*)d_in[5];
    const float* Wk  = (const float*)d_in[6];
    const float* Wv  = (const float*)d_in[7];
    const float* vg  = (const float*)d_in[8];
    const float* vb  = (const float*)d_in[9];
    const float* vm  = (const float*)d_in[10];
    const float* vva = (const float*)d_in[11];
    const float* emb = (const float*)d_in[12];
    float* out = (float*)d_out;

    float* kbuf = (float*)d_ws;                              // 16*16*2048 f32 (exp)
    float* lcb  = kbuf + (size_t)BB * 16 * LLN;              // 16*16*128 f32
    unsigned short* qb16 = (unsigned short*)(lcb + (size_t)BB * 16 * 128);  // 16*64*2048 u16
    unsigned short* vb16 = qb16 + (size_t)BB * 64 * LLN;     // 16*128*2048 u16
    unsigned short* Wpk  = vb16 + (size_t)BB * 128 * LLN;    // 64*6144 u16
    unsigned short* xpk  = Wpk + (size_t)64 * WIMG_U16;      // 256*2050*32 u16 (~33.6 MB)

    hipLaunchKernelGGL(prep_all, dim3(8, 16, 17), dim3(256), 0, stream,
                       x, Wq, Wk, Wv, xpk, Wpk);

    hipLaunchKernelGGL(conv_mfma, dim3(16, 4, 16), dim3(256), 0, stream,
                       xpk, Wpk, qg, qb, qm, qv, vg, vb, vm, vva,
                       qb16, kbuf, vb16);

    hipLaunchKernelGGL(lambdac_kernel, dim3(512), dim3(256), 0, stream,
                       kbuf, vb16, lcb);

    hipLaunchKernelGGL(final_kernel, dim3(32, BB), dim3(256), 0, stream,
                       qb16, vb16, lcb, emb, out);
}

// Round 7
// 191.429 us; speedup vs baseline: 1.0430x; 1.0430x over previous
//
#include <hip/hip_runtime.h>

#define BB 16
#define CIN 512
#define LLN 2048
#define EPSV 1e-5f

typedef __attribute__((ext_vector_type(8))) short bf16x8s;
typedef __attribute__((ext_vector_type(4))) float f32x4;

__device__ __forceinline__ unsigned short f2bf(float f) {
    union { float f; unsigned int i; } c; c.f = f;
    unsigned int x = c.i;
    unsigned int lsb = (x >> 16) & 1;
    x += 0x7fff + lsb;            // RNE
    return (unsigned short)(x >> 16);
}
__device__ __forceinline__ unsigned int pack2bf(float a, float b) {
    return (unsigned int)f2bf(a) | ((unsigned int)f2bf(b) << 16);
}
__device__ __forceinline__ float bf2f(unsigned short u) {
    union { unsigned int i; float f; } c; c.i = ((unsigned int)u) << 16; return c.f;
}
__device__ __forceinline__ float bflo(unsigned int w) {
    union { unsigned int i; float f; } c; c.i = w << 16; return c.f;
}
__device__ __forceinline__ float bfhi(unsigned int w) {
    union { unsigned int i; float f; } c; c.i = w & 0xffff0000u; return c.f;
}

// async global->LDS, 16B per lane, LDS dest = wave-uniform base + lane*16
__device__ __forceinline__ void g2l16(const void* g, void* l) {
    typedef const __attribute__((address_space(1))) unsigned int GU;
    typedef __attribute__((address_space(3))) unsigned int LU;
    __builtin_amdgcn_global_load_lds((GU*)g, (LU*)l, 16, 0, 0);
}

// ---------------- Kernel 0: prep (x repack + weight repack, one dispatch) ----
// xpk: [b][chunk 16][rp 2050][32 u16], rp = n+1 (rows 0,2049 zero halo); logical
// ci-group g (8 ci) of row rp is stored at 16B slot (g ^ ((rp>>1)&3)).
// Wpk: [cot 4][chunk 16] images of [t 3][cf 4][lane 64][e 8] bf16 (6144 u16):
//   lane holds W[co=cot*64+cf*16+(lane&15)][ci0+(lane>>4)*8+e][t] (frag-contig:
//   in conv, ds_read_b128 at lane*16 gives each lane its MFMA A-fragment).
#define WIMG_U16 6144

__global__ __launch_bounds__(256) void prep_all(
    const float* __restrict__ x,
    const float* __restrict__ Wq, const float* __restrict__ Wk,
    const float* __restrict__ Wv,
    unsigned short* __restrict__ xpk, unsigned short* __restrict__ Wpk)
{
    const int tid = threadIdx.x;
    if (blockIdx.z < 16) {
        // ---- x repack: block = (n-tile 256, ci-chunk, b), 2048 blocks ----
        __shared__ __align__(16) unsigned int xs[256 * 16];   // 16 KB: [nl][16 u32]
        const int nt = blockIdx.x;   // 0..7
        const int c  = blockIdx.y;   // 0..15
        const int b  = blockIdx.z;   // 0..15
        const int n0 = nt * 256;
        const int p  = tid >> 4;         // ci pair 0..15
        const int ns = (tid & 15) * 4;   // n_local base
        const int g = p >> 2, pi = p & 3;
        const float* x0 = x + ((size_t)b * CIN + (size_t)(c * 32 + 2 * p)) * LLN + n0;
#pragma unroll
        for (int j = 0; j < 4; j++) {
            int nl = ns + j * 64;
            float4 a = *(const float4*)&x0[nl];
            float4 bq = *(const float4*)&x0[LLN + nl];
            int rp = n0 + nl + 1;
            xs[(nl + 0) * 16 + (g ^ (((rp + 0) >> 1) & 3)) * 4 + pi] = pack2bf(a.x, bq.x);
            xs[(nl + 1) * 16 + (g ^ (((rp + 1) >> 1) & 3)) * 4 + pi] = pack2bf(a.y, bq.y);
            xs[(nl + 2) * 16 + (g ^ (((rp + 2) >> 1) & 3)) * 4 + pi] = pack2bf(a.z, bq.z);
            xs[(nl + 3) * 16 + (g ^ (((rp + 3) >> 1) & 3)) * 4 + pi] = pack2bf(a.w, bq.w);
        }
        __syncthreads();
        // coalesced copy-out: 16 KB contiguous (rows n0+1 .. n0+256)
        uint4* dst = (uint4*)(xpk + ((size_t)(b * 16 + c) * 2050 + n0 + 1) * 32);
        const uint4* srcl = (const uint4*)xs;
#pragma unroll
        for (int k = 0; k < 4; k++)
            dst[tid + k * 256] = srcl[tid + k * 256];
        // zero halo rows rp=0 and rp=2049
        if (nt == 0 && tid < 4)
            *(uint4*)(xpk + ((size_t)(b * 16 + c) * 2050) * 32 + tid * 8) = make_uint4(0, 0, 0, 0);
        if (nt == 7 && tid < 4)
            *(uint4*)(xpk + ((size_t)(b * 16 + c) * 2050 + 2049) * 32 + tid * 8) = make_uint4(0, 0, 0, 0);
    } else {
        // ---- weight repack: 128 blocks, half an image each ----
        const int wblk = blockIdx.y * 8 + blockIdx.x;   // 0..127
        const int img = wblk >> 1, half = wblk & 1;     // img = cot*16 + chunk
        const int cot = img >> 4, chunk = img & 15;
        const int ci0 = chunk * 32;
        for (int i = half * 3072 + tid; i < half * 3072 + 3072; i += 256) {
            int t = i >> 11, r = i & 2047;
            int cf = r >> 9, lane = (r >> 3) & 63, e = i & 7;
            int lm = lane & 15, kq = lane >> 4;
            int cop = cot * 64 + cf * 16 + lm;
            int cig = ci0 + kq * 8 + e;
            float val = 0.f;
            if (cop < 64)        val = Wq[((size_t)cop * 512 + cig) * 3 + t];
            else if (cop < 80)   val = Wk[((size_t)(cop - 64) * 512 + cig) * 3 + t];
            else if (cop < 208)  val = Wv[((size_t)(cop - 80) * 512 + cig) * 3 + t];
            Wpk[(size_t)img * WIMG_U16 + i] = f2bf(val);
        }
    }
}

// ---------------- Kernel 1: MFMA conv (q|k|v) + BN, double-buffered ----------
// Block: 64 co x 256 n, 512 threads = 8 waves (each 64co x 32n), 16 chunks of
// 32 ci. LDS 57.6 KB -> 2 blocks/CU = 16 waves/CU (2x the 256-thread variant's
// latency-hiding pool). Weights staged to LDS via global_load_lds (frag-contig
// image, conflict-free ds_read_b128). q,v stored bf16; k stored exp(score-16).
__global__ __launch_bounds__(512, 4) void conv_mfma(
    const unsigned short* __restrict__ xpk, const unsigned short* __restrict__ Wpk,
    const float* __restrict__ qg, const float* __restrict__ qb,
    const float* __restrict__ qm, const float* __restrict__ qv,
    const float* __restrict__ vg, const float* __restrict__ vb,
    const float* __restrict__ vm, const float* __restrict__ vvar,
    unsigned short* __restrict__ qb16, float* __restrict__ kbuf,
    unsigned short* __restrict__ vb16)
{
    __shared__ __align__(16) unsigned short xT[2][258 * 32];   // 2 x 16512 B
    __shared__ __align__(16) unsigned short wA[2][WIMG_U16];   // 2 x 12288 B
    __shared__ float sscale[64], sshift[64];

    const int tid = threadIdx.x;
    const int wave = tid >> 6, lane = tid & 63;
    const int kq = lane >> 4, lm = lane & 15;
    const int n0 = blockIdx.x * 256;
    const int cot = blockIdx.y;          // 0..3 (64 co each)
    const int b = blockIdx.z;

    const unsigned short* xpanel = xpk + ((size_t)b * 16 * 2050 + n0) * 32;
    const unsigned short* wbase  = Wpk + (size_t)cot * 16 * WIMG_U16;

#define STAGE(buf, chunk)                                                      \
    {                                                                          \
        const unsigned short* wsrc = wbase + (size_t)(chunk) * WIMG_U16;       \
        const unsigned short* xsrc = xpanel + (size_t)(chunk) * 2050 * 32;     \
        for (int i = tid; i < 768; i += 512)  g2l16(wsrc + (size_t)i * 8, &wA[buf][i * 8]); \
        for (int i = tid; i < 1032; i += 512) g2l16(xsrc + (size_t)i * 8, &xT[buf][i * 8]); \
    }

    STAGE(0, 0)

    if (tid < 64) {                      // BN prep overlaps prologue loads
        int cop = cot * 64 + tid;
        float sc = 1.f, sh = 0.f;
        if (cop < 64) {
            float g = qg[cop], be = qb[cop], m = qm[cop], va = qv[cop];
            sc = g * rsqrtf(va + EPSV); sh = be - m * sc;
        } else if (cop >= 80 && cop < 208) {
            int cc = cop - 80;
            float g = vg[cc], be = vb[cc], m = vm[cc], va = vvar[cc];
            sc = g * rsqrtf(va + EPSV); sh = be - m * sc;
        }
        sscale[tid] = sc; sshift[tid] = sh;
    }

    f32x4 acc[4][2];
#pragma unroll
    for (int i = 0; i < 4; i++)
#pragma unroll
        for (int j = 0; j < 2; j++) acc[i][j] = (f32x4){0.f, 0.f, 0.f, 0.f};

    asm volatile("s_waitcnt vmcnt(0)" ::: "memory");
    __syncthreads();

    for (int chunk = 0; chunk < 16; chunk++) {
        const int cur = chunk & 1;
        if (chunk < 15) STAGE(cur ^ 1, chunk + 1)

#pragma unroll
        for (int t = 0; t < 3; t++) {
            bf16x8s aF[4];
#pragma unroll
            for (int cf = 0; cf < 4; cf++)
                aF[cf] = *(const bf16x8s*)&wA[cur][((t * 4 + cf) * 64 + lane) * 8];
#pragma unroll
            for (int fn = 0; fn < 2; fn++) {
                int lr = wave * 32 + fn * 16 + lm + t;
                int grp = kq ^ ((lr >> 1) & 3);       // matches prep pre-swizzle
                bf16x8s bF = *(const bf16x8s*)&xT[cur][lr * 32 + grp * 8];
#pragma unroll
                for (int cf = 0; cf < 4; cf++)
                    acc[cf][fn] = __builtin_amdgcn_mfma_f32_16x16x32_bf16(
                        aF[cf], bF, acc[cf][fn], 0, 0, 0);
            }
        }
        asm volatile("s_waitcnt vmcnt(0)" ::: "memory");
        __syncthreads();
    }
#undef STAGE

    // epilogue: C layout col=lane&15 (n), row=(lane>>4)*4+reg (co)
#pragma unroll
    for (int cf = 0; cf < 4; cf++) {
#pragma unroll
        for (int fn = 0; fn < 2; fn++) {
#pragma unroll
            for (int r = 0; r < 4; r++) {
                int col = cf * 16 + kq * 4 + r;        // co_local 0..63
                int cop = cot * 64 + col;
                if (cop >= 208) continue;
                float val = acc[cf][fn][r] * sscale[col] + sshift[col];
                int nout = n0 + wave * 32 + fn * 16 + lm;
                if (cop < 64)
                    qb16[((size_t)b * 64 + cop) * LLN + nout] = f2bf(val);
                else if (cop < 80)
                    kbuf[((size_t)b * 16 + (cop - 64)) * LLN + nout] = __expf(val - 16.f);
                else
                    vb16[((size_t)b * 128 + (cop - 80)) * LLN + nout] = f2bf(val);
            }
        }
    }
}

// ---------------- Kernel 2: lambda_c from pre-exponentiated scores ----------
// kbuf already holds exp(score-16); softmax = ratio of sums, so a SINGLE pass:
// lambda_c[b][k][v] = (sum_n e[k][n]*v[v][n]) / (sum_n e[k][n]).
// block = (b, v-group-of-4); wave owns 4 k-rows. v read as bf16 x8.
__global__ __launch_bounds__(256) void lambdac_kernel(
    const float* __restrict__ kexp, const unsigned short* __restrict__ vb16,
    float* __restrict__ lcb)
{
    const int wave = threadIdx.x >> 6;
    const int lane = threadIdx.x & 63;
    const int b = blockIdx.x >> 5;
    const int vg = blockIdx.x & 31;
    const float* ps = kexp + ((size_t)b * 16 + wave * 4) * LLN;
    const unsigned short* pv = vb16 + ((size_t)b * 128 + vg * 4) * LLN;

    float sum[4] = {0.f, 0.f, 0.f, 0.f};
    float acc[4][4];
#pragma unroll
    for (int k = 0; k < 4; k++)
#pragma unroll
        for (int v = 0; v < 4; v++) acc[k][v] = 0.f;
#pragma unroll
    for (int j = 0; j < 4; j++) {
        int n = (j * 64 + lane) * 8;
        float e[4][8];
#pragma unroll
        for (int k = 0; k < 4; k++) {
            float4 a = *(const float4*)&ps[(size_t)k * LLN + n];
            float4 c = *(const float4*)&ps[(size_t)k * LLN + n + 4];
            e[k][0] = a.x; e[k][1] = a.y; e[k][2] = a.z; e[k][3] = a.w;
            e[k][4] = c.x; e[k][5] = c.y; e[k][6] = c.z; e[k][7] = c.w;
            sum[k] += a.x + a.y + a.z + a.w + c.x + c.y + c.z + c.w;
        }
#pragma unroll
        for (int v = 0; v < 4; v++) {
            uint4 w = *(const uint4*)&pv[(size_t)v * LLN + n];
            float vv[8] = {bflo(w.x), bfhi(w.x), bflo(w.y), bfhi(w.y),
                           bflo(w.z), bfhi(w.z), bflo(w.w), bfhi(w.w)};
#pragma unroll
            for (int k = 0; k < 4; k++) {
                float t = 0.f;
#pragma unroll
                for (int q = 0; q < 8; q++) t += e[k][q] * vv[q];
                acc[k][v] += t;
            }
        }
    }
#pragma unroll
    for (int k = 0; k < 4; k++) {
#pragma unroll
        for (int off = 32; off > 0; off >>= 1)
            sum[k] += __shfl_xor(sum[k], off, 64);
#pragma unroll
        for (int v = 0; v < 4; v++)
#pragma unroll
            for (int off = 32; off > 0; off >>= 1)
                acc[k][v] += __shfl_xor(acc[k][v], off, 64);
    }
    if (lane == 0) {
#pragma unroll
        for (int k = 0; k < 4; k++) {
            float inv = 1.f / sum[k];
#pragma unroll
            for (int v = 0; v < 4; v++)
                lcb[((size_t)b * 16 + wave * 4 + k) * 128 + vg * 4 + v] = acc[k][v] * inv;
        }
    }
}

// ---------------- Kernel 3: output, all 4 heads fused ----------------
// out[b][h*128+v][n] = sum_k q[b][h*16+k][n]*lc[b][k][v] + (sum_k q*emb[k])*v[b][v][n]
// block = (n-tile 64, b); wave = head. q,v read as bf16.
// Writes 268 MB fp32 -> HBM-bound (~43 us floor); stores are fully coalesced.
__global__ __launch_bounds__(256) void final_kernel(
    const unsigned short* __restrict__ qb16, const unsigned short* __restrict__ vb16,
    const float* __restrict__ lcb, const float* __restrict__ emb,
    float* __restrict__ out)
{
    __shared__ float lcsT[128][16];   // transposed: row v, 16 k contiguous
    __shared__ float es[16];
    const int tid = threadIdx.x;
    const int h = tid >> 6, nl = tid & 63;
    const int n0 = blockIdx.x * 64;   // 32 tiles
    const int b = blockIdx.y;

    for (int i = tid; i < 2048; i += 256)
        lcsT[i >> 4][i & 15] = lcb[(size_t)b * 2048 + (size_t)(i & 15) * 128 + (i >> 4)];
    if (tid < 16) es[tid] = emb[tid];
    __syncthreads();

    const int n = n0 + nl;
    const unsigned short* pq = qb16 + ((size_t)b * 64 + h * 16) * LLN + n;
    float4 q4[4];
#pragma unroll
    for (int kk = 0; kk < 4; kk++) {
        q4[kk].x = bf2f(pq[(size_t)(kk * 4 + 0) * LLN]);
        q4[kk].y = bf2f(pq[(size_t)(kk * 4 + 1) * LLN]);
        q4[kk].z = bf2f(pq[(size_t)(kk * 4 + 2) * LLN]);
        q4[kk].w = bf2f(pq[(size_t)(kk * 4 + 3) * LLN]);
    }
    float s = 0.f;
#pragma unroll
    for (int kk = 0; kk < 4; kk++)
        s += q4[kk].x * es[kk * 4] + q4[kk].y * es[kk * 4 + 1]
           + q4[kk].z * es[kk * 4 + 2] + q4[kk].w * es[kk * 4 + 3];

    const unsigned short* pv = vb16 + (size_t)b * 128 * LLN + n;
    float* po = out + ((size_t)b * 512 + h * 128) * LLN + n;
#pragma unroll 4
    for (int v = 0; v < 128; v++) {
        float4 c0 = *(const float4*)&lcsT[v][0];
        float4 c1 = *(const float4*)&lcsT[v][4];
        float4 c2 = *(const float4*)&lcsT[v][8];
        float4 c3 = *(const float4*)&lcsT[v][12];
        float lam = q4[0].x * c0.x + q4[0].y * c0.y + q4[0].z * c0.z + q4[0].w * c0.w
                  + q4[1].x * c1.x + q4[1].y * c1.y + q4[1].z * c1.z + q4[1].w * c1.w
                  + q4[2].x * c2.x + q4[2].y * c2.y + q4[2].z * c2.z + q4[2].w * c2.w
                  + q4[3].x * c3.x + q4[3].y * c3.y + q4[3].z * c3.z + q4[3].w * c3.w;
        float vvv = bf2f(pv[(size_t)v * LLN]);
        po[(size_t)v * LLN] = lam + s * vvv;
    }
}

extern "C" void kernel_launch(void* const* d_in, const int* in_sizes, int n_in,
                              void* d_out, int out_size, void* d_ws, size_t ws_size,
                              hipStream_t stream)
{
    const float* x   = (const float*)d_in[0];
    const float* Wq  = (const float*)d_in[1];
    const float* qg  = (const float*)d_in[2];
    const float* qb  = (const float*)d_in[3];
    const float* qm  = (const float*)d_in[4];
    const float* qv  = (const float*)d_in[5];
    const float* Wk  = (const float*)d_in[6];
    const float* Wv  = (const float*)d_in[7];
    const float* vg  = (const float*)d_in[8];
    const float* vb  = (const float*)d_in[9];
    const float* vm  = (const float*)d_in[10];
    const float* vva = (const float*)d_in[11];
    const float* emb = (const float*)d_in[12];
    float* out = (float*)d_out;

    float* kbuf = (float*)d_ws;                              // 16*16*2048 f32 (exp)
    float* lcb  = kbuf + (size_t)BB * 16 * LLN;              // 16*16*128 f32
    unsigned short* qb16 = (unsigned short*)(lcb + (size_t)BB * 16 * 128);  // 16*64*2048 u16
    unsigned short* vb16 = qb16 + (size_t)BB * 64 * LLN;     // 16*128*2048 u16
    unsigned short* Wpk  = vb16 + (size_t)BB * 128 * LLN;    // 64*6144 u16
    unsigned short* xpk  = Wpk + (size_t)64 * WIMG_U16;      // 256*2050*32 u16 (~33.6 MB)

    hipLaunchKernelGGL(prep_all, dim3(8, 16, 17), dim3(256), 0, stream,
                       x, Wq, Wk, Wv, xpk, Wpk);

    hipLaunchKernelGGL(conv_mfma, dim3(8, 4, 16), dim3(512), 0, stream,
                       xpk, Wpk, qg, qb, qm, qv, vg, vb, vm, vva,
                       qb16, kbuf, vb16);

    hipLaunchKernelGGL(lambdac_kernel, dim3(512), dim3(256), 0, stream,
                       kbuf, vb16, lcb);

    hipLaunchKernelGGL(final_kernel, dim3(32, BB), dim3(256), 0, stream,
                       qb16, vb16, lcb, emb, out);
}

// Round 9
// 190.794 us; speedup vs baseline: 1.0464x; 1.0033x over previous
//
#include <hip/hip_runtime.h>

#define BB 16
#define CIN 512
#define LLN 2048
#define EPSV 1e-5f
#define WIMG_U16 6144

typedef __attribute__((ext_vector_type(8))) short bf16x8s;
typedef __attribute__((ext_vector_type(4))) float f32x4;

__device__ __forceinline__ unsigned short f2bf(float f) {
    union { float f; unsigned int i; } c; c.f = f;
    unsigned int x = c.i;
    unsigned int lsb = (x >> 16) & 1;
    x += 0x7fff + lsb;            // RNE
    return (unsigned short)(x >> 16);
}
__device__ __forceinline__ unsigned int pack2bf(float a, float b) {
    return (unsigned int)f2bf(a) | ((unsigned int)f2bf(b) << 16);
}
__device__ __forceinline__ float bf2f(unsigned short u) {
    union { unsigned int i; float f; } c; c.i = ((unsigned int)u) << 16; return c.f;
}
__device__ __forceinline__ float bflo(unsigned int w) {
    union { unsigned int i; float f; } c; c.i = w << 16; return c.f;
}
__device__ __forceinline__ float bfhi(unsigned int w) {
    union { unsigned int i; float f; } c; c.i = w & 0xffff0000u; return c.f;
}

// async global->LDS, 16B per lane, LDS dest = wave-uniform base + lane*16
__device__ __forceinline__ void g2l16(const void* g, void* l) {
    typedef const __attribute__((address_space(1))) unsigned int GU;
    typedef __attribute__((address_space(3))) unsigned int LU;
    __builtin_amdgcn_global_load_lds((GU*)g, (LU*)l, 16, 0, 0);
}

// ---------------- Kernel 0: prep (x repack + weight repack, one dispatch) ----
// xpk: [b][chunk 16][rp 2050][32 u16], rp = n+1 (rows 0,2049 zero halo); logical
// ci-group g (8 ci) of row rp is stored at 16B slot (g ^ ((rp>>1)&3)).
// Wpk: [cot 4][chunk 16] images of [t 3][cf 4][lane 64][e 8] bf16 (frag-contig:
// in conv, ds_read_b128 at lane*16 gives each lane its MFMA A-fragment).
__global__ __launch_bounds__(256) void prep_all(
    const float* __restrict__ x,
    const float* __restrict__ Wq, const float* __restrict__ Wk,
    const float* __restrict__ Wv,
    unsigned short* __restrict__ xpk, unsigned short* __restrict__ Wpk)
{
    const int tid = threadIdx.x;
    if (blockIdx.z < 16) {
        // ---- x repack: block = (n-tile 256, ci-chunk, b), 2048 blocks ----
        __shared__ __align__(16) unsigned int xs[256 * 16];   // 16 KB: [nl][16 u32]
        const int nt = blockIdx.x;   // 0..7
        const int c  = blockIdx.y;   // 0..15
        const int b  = blockIdx.z;   // 0..15
        const int n0 = nt * 256;
        const int p  = tid >> 4;         // ci pair 0..15
        const int ns = (tid & 15) * 4;   // n_local base
        const int g = p >> 2, pi = p & 3;
        const float* x0 = x + ((size_t)b * CIN + (size_t)(c * 32 + 2 * p)) * LLN + n0;
#pragma unroll
        for (int j = 0; j < 4; j++) {
            int nl = ns + j * 64;
            float4 a = *(const float4*)&x0[nl];
            float4 bq = *(const float4*)&x0[LLN + nl];
            int rp = n0 + nl + 1;
            xs[(nl + 0) * 16 + (g ^ (((rp + 0) >> 1) & 3)) * 4 + pi] = pack2bf(a.x, bq.x);
            xs[(nl + 1) * 16 + (g ^ (((rp + 1) >> 1) & 3)) * 4 + pi] = pack2bf(a.y, bq.y);
            xs[(nl + 2) * 16 + (g ^ (((rp + 2) >> 1) & 3)) * 4 + pi] = pack2bf(a.z, bq.z);
            xs[(nl + 3) * 16 + (g ^ (((rp + 3) >> 1) & 3)) * 4 + pi] = pack2bf(a.w, bq.w);
        }
        __syncthreads();
        // coalesced copy-out: 16 KB contiguous (rows n0+1 .. n0+256)
        uint4* dst = (uint4*)(xpk + ((size_t)(b * 16 + c) * 2050 + n0 + 1) * 32);
        const uint4* srcl = (const uint4*)xs;
#pragma unroll
        for (int k = 0; k < 4; k++)
            dst[tid + k * 256] = srcl[tid + k * 256];
        // zero halo rows rp=0 and rp=2049
        if (nt == 0 && tid < 4)
            *(uint4*)(xpk + ((size_t)(b * 16 + c) * 2050) * 32 + tid * 8) = make_uint4(0, 0, 0, 0);
        if (nt == 7 && tid < 4)
            *(uint4*)(xpk + ((size_t)(b * 16 + c) * 2050 + 2049) * 32 + tid * 8) = make_uint4(0, 0, 0, 0);
    } else {
        // ---- weight repack: 128 blocks, half an image each ----
        const int wblk = blockIdx.y * 8 + blockIdx.x;   // 0..127
        const int img = wblk >> 1, half = wblk & 1;     // img = cot*16 + chunk
        const int cot = img >> 4, chunk = img & 15;
        const int ci0 = chunk * 32;
        for (int i = half * 3072 + tid; i < half * 3072 + 3072; i += 256) {
            int t = i >> 11, r = i & 2047;
            int cf = r >> 9, lane = (r >> 3) & 63, e = i & 7;
            int lm = lane & 15, kq = lane >> 4;
            int cop = cot * 64 + cf * 16 + lm;
            int cig = ci0 + kq * 8 + e;
            float val = 0.f;
            if (cop < 64)        val = Wq[((size_t)cop * 512 + cig) * 3 + t];
            else if (cop < 80)   val = Wk[((size_t)(cop - 64) * 512 + cig) * 3 + t];
            else if (cop < 208)  val = Wv[((size_t)(cop - 80) * 512 + cig) * 3 + t];
            Wpk[(size_t)img * WIMG_U16 + i] = f2bf(val);
        }
    }
}

// ---------------- Kernel 1: MFMA conv (q|k|v) + BN, double-buffered ----------
// Block: 64 co x 256 n, 512 threads = 8 waves (each 64co x 32n), 16 chunks of
// 32 ci. LDS 57.6 KB -> 2 blocks/CU = 16 waves/CU. Weights staged via
// global_load_lds (frag-contig image, conflict-free ds_read_b128).
// q,v stored bf16; k stored exp(score-16) (softmax becomes ratio of sums).
__global__ __launch_bounds__(512, 4) void conv_mfma(
    const unsigned short* __restrict__ xpk, const unsigned short* __restrict__ Wpk,
    const float* __restrict__ qg, const float* __restrict__ qb,
    const float* __restrict__ qm, const float* __restrict__ qv,
    const float* __restrict__ vg, const float* __restrict__ vb,
    const float* __restrict__ vm, const float* __restrict__ vvar,
    unsigned short* __restrict__ qb16, float* __restrict__ kbuf,
    unsigned short* __restrict__ vb16)
{
    __shared__ __align__(16) unsigned short xT[2][258 * 32];   // 2 x 16512 B
    __shared__ __align__(16) unsigned short wA[2][WIMG_U16];   // 2 x 12288 B
    __shared__ float sscale[64], sshift[64];

    const int tid = threadIdx.x;
    const int wave = tid >> 6, lane = tid & 63;
    const int kq = lane >> 4, lm = lane & 15;
    const int n0 = blockIdx.x * 256;
    const int cot = blockIdx.y;          // 0..3 (64 co each)
    const int b = blockIdx.z;

    const unsigned short* xpanel = xpk + ((size_t)b * 16 * 2050 + n0) * 32;
    const unsigned short* wbase  = Wpk + (size_t)cot * 16 * WIMG_U16;

#define STAGE(buf, chunk)                                                      \
    {                                                                          \
        const unsigned short* wsrc = wbase + (size_t)(chunk) * WIMG_U16;       \
        const unsigned short* xsrc = xpanel + (size_t)(chunk) * 2050 * 32;     \
        for (int i = tid; i < 768; i += 512)  g2l16(wsrc + (size_t)i * 8, &wA[buf][i * 8]); \
        for (int i = tid; i < 1032; i += 512) g2l16(xsrc + (size_t)i * 8, &xT[buf][i * 8]); \
    }

    STAGE(0, 0)

    if (tid < 64) {                      // BN prep overlaps prologue loads
        int cop = cot * 64 + tid;
        float sc = 1.f, sh = 0.f;
        if (cop < 64) {
            float g = qg[cop], be = qb[cop], m = qm[cop], va = qv[cop];
            sc = g * rsqrtf(va + EPSV); sh = be - m * sc;
        } else if (cop >= 80 && cop < 208) {
            int cc = cop - 80;
            float g = vg[cc], be = vb[cc], m = vm[cc], va = vvar[cc];
            sc = g * rsqrtf(va + EPSV); sh = be - m * sc;
        }
        sscale[tid] = sc; sshift[tid] = sh;
    }

    f32x4 acc[4][2];
#pragma unroll
    for (int i = 0; i < 4; i++)
#pragma unroll
        for (int j = 0; j < 2; j++) acc[i][j] = (f32x4){0.f, 0.f, 0.f, 0.f};

    asm volatile("s_waitcnt vmcnt(0)" ::: "memory");
    __syncthreads();

    for (int chunk = 0; chunk < 16; chunk++) {
        const int cur = chunk & 1;
        if (chunk < 15) STAGE(cur ^ 1, chunk + 1)

#pragma unroll
        for (int t = 0; t < 3; t++) {
            bf16x8s aF[4];
#pragma unroll
            for (int cf = 0; cf < 4; cf++)
                aF[cf] = *(const bf16x8s*)&wA[cur][((t * 4 + cf) * 64 + lane) * 8];
#pragma unroll
            for (int fn = 0; fn < 2; fn++) {
                int lr = wave * 32 + fn * 16 + lm + t;
                int grp = kq ^ ((lr >> 1) & 3);       // matches prep pre-swizzle
                bf16x8s bF = *(const bf16x8s*)&xT[cur][lr * 32 + grp * 8];
#pragma unroll
                for (int cf = 0; cf < 4; cf++)
                    acc[cf][fn] = __builtin_amdgcn_mfma_f32_16x16x32_bf16(
                        aF[cf], bF, acc[cf][fn], 0, 0, 0);
            }
        }
        asm volatile("s_waitcnt vmcnt(0)" ::: "memory");
        __syncthreads();
    }
#undef STAGE

    // epilogue: C layout col=lane&15 (n), row=(lane>>4)*4+reg (co)
#pragma unroll
    for (int cf = 0; cf < 4; cf++) {
#pragma unroll
        for (int fn = 0; fn < 2; fn++) {
#pragma unroll
            for (int r = 0; r < 4; r++) {
                int col = cf * 16 + kq * 4 + r;        // co_local 0..63
                int cop = cot * 64 + col;
                if (cop >= 208) continue;
                float val = acc[cf][fn][r] * sscale[col] + sshift[col];
                int nout = n0 + wave * 32 + fn * 16 + lm;
                if (cop < 64)
                    qb16[((size_t)b * 64 + cop) * LLN + nout] = f2bf(val);
                else if (cop < 80)
                    kbuf[((size_t)b * 16 + (cop - 64)) * LLN + nout] = __expf(val - 16.f);
                else
                    vb16[((size_t)b * 128 + (cop - 80)) * LLN + nout] = f2bf(val);
            }
        }
    }
}

// ---------------- Kernel 2: lambda_c partials (n-split, no atomics) ---------
// kbuf holds exp(score-16). Each block reduces HALF the n-range:
//   lc2[half][b][k][v] = sum_{n in half} e[k][n]*v[v][n]
//   s2 [half][b][k]    = sum_{n in half} e[k][n]        (written by vg==0)
// final combines (l0+l1)/(s0+s1). grid 1024 = 4 blocks/CU (2x r7 occupancy).
__global__ __launch_bounds__(256) void lambdac_kernel(
    const float* __restrict__ kexp, const unsigned short* __restrict__ vb16,
    float* __restrict__ lc2, float* __restrict__ s2)
{
    const int wave = threadIdx.x >> 6;
    const int lane = threadIdx.x & 63;
    const int idx = blockIdx.x;          // 0..1023
    const int half = idx & 1;
    const int vgp = (idx >> 1) & 31;
    const int b = idx >> 6;
    const float* ps = kexp + ((size_t)b * 16 + wave * 4) * LLN + half * 1024;
    const unsigned short* pv = vb16 + ((size_t)b * 128 + vgp * 4) * LLN + half * 1024;

    float sum[4] = {0.f, 0.f, 0.f, 0.f};
    float acc[4][4];
#pragma unroll
    for (int k = 0; k < 4; k++)
#pragma unroll
        for (int v = 0; v < 4; v++) acc[k][v] = 0.f;
#pragma unroll
    for (int j = 0; j < 2; j++) {
        int n = (j * 64 + lane) * 8;
        float e[4][8];
#pragma unroll
        for (int k = 0; k < 4; k++) {
            float4 a = *(const float4*)&ps[(size_t)k * LLN + n];
            float4 c = *(const float4*)&ps[(size_t)k * LLN + n + 4];
            e[k][0] = a.x; e[k][1] = a.y; e[k][2] = a.z; e[k][3] = a.w;
            e[k][4] = c.x; e[k][5] = c.y; e[k][6] = c.z; e[k][7] = c.w;
            sum[k] += a.x + a.y + a.z + a.w + c.x + c.y + c.z + c.w;
        }
#pragma unroll
        for (int v = 0; v < 4; v++) {
            uint4 w = *(const uint4*)&pv[(size_t)v * LLN + n];
            float vv[8] = {bflo(w.x), bfhi(w.x), bflo(w.y), bfhi(w.y),
                           bflo(w.z), bfhi(w.z), bflo(w.w), bfhi(w.w)};
#pragma unroll
            for (int k = 0; k < 4; k++) {
                float t = 0.f;
#pragma unroll
                for (int q = 0; q < 8; q++) t += e[k][q] * vv[q];
                acc[k][v] += t;
            }
        }
    }
#pragma unroll
    for (int k = 0; k < 4; k++) {
#pragma unroll
        for (int off = 32; off > 0; off >>= 1)
            sum[k] += __shfl_xor(sum[k], off, 64);
#pragma unroll
        for (int v = 0; v < 4; v++)
#pragma unroll
            for (int off = 32; off > 0; off >>= 1)
                acc[k][v] += __shfl_xor(acc[k][v], off, 64);
    }
    if (lane == 0) {
#pragma unroll
        for (int k = 0; k < 4; k++) {
#pragma unroll
            for (int v = 0; v < 4; v++)
                lc2[(((size_t)half * 16 + b) * 16 + wave * 4 + k) * 128 + vgp * 4 + v]
                    = acc[k][v];
            if (vgp == 0)
                s2[((size_t)half * 16 + b) * 16 + wave * 4 + k] = sum[k];
        }
    }
}

// ---------------- Kernel 3: output, v-split for occupancy ----------------
// out[b][h*128+v][n] = sum_k q*lc[k][v] + (sum_k q*emb[k])*v[b][v][n]
// block = (n-tile 64, v-half, b) = 1024 blocks = 4/CU; wave = head.
// Combines lambda_c partials: lc = (l0+l1)/(s0+s1), folded into LDS fill.
__global__ __launch_bounds__(256) void final_kernel(
    const unsigned short* __restrict__ qb16, const unsigned short* __restrict__ vb16,
    const float* __restrict__ lc2, const float* __restrict__ s2,
    const float* __restrict__ emb, float* __restrict__ out)
{
    __shared__ float lcsT[64][16];    // row v_local, 16 k contiguous
    __shared__ float es[16], invd[16];
    const int tid = threadIdx.x;
    const int h = tid >> 6, nl = tid & 63;
    const int n0 = blockIdx.x * 64;   // 32 tiles
    const int vh = blockIdx.y * 64;   // v-half
    const int b = blockIdx.z;

    if (tid < 16) {
        es[tid] = emb[tid];
        invd[tid] = 1.f / (s2[(size_t)b * 16 + tid] + s2[256 + (size_t)b * 16 + tid]);
    }
    __syncthreads();
    for (int i = tid; i < 1024; i += 256) {
        int k = i & 15, vl = i >> 4;
        float l0 = lc2[((size_t)b * 16 + k) * 128 + vh + vl];
        float l1 = lc2[(size_t)32768 + ((size_t)b * 16 + k) * 128 + vh + vl];
        lcsT[vl][k] = (l0 + l1) * invd[k];
    }
    __syncthreads();

    const int n = n0 + nl;
    const unsigned short* pq = qb16 + ((size_t)b * 64 + h * 16) * LLN + n;
    float4 q4[4];
#pragma unroll
    for (int kk = 0; kk < 4; kk++) {
        q4[kk].x = bf2f(pq[(size_t)(kk * 4 + 0) * LLN]);
        q4[kk].y = bf2f(pq[(size_t)(kk * 4 + 1) * LLN]);
        q4[kk].z = bf2f(pq[(size_t)(kk * 4 + 2) * LLN]);
        q4[kk].w = bf2f(pq[(size_t)(kk * 4 + 3) * LLN]);
    }
    float s = 0.f;
#pragma unroll
    for (int kk = 0; kk < 4; kk++)
        s += q4[kk].x * es[kk * 4] + q4[kk].y * es[kk * 4 + 1]
           + q4[kk].z * es[kk * 4 + 2] + q4[kk].w * es[kk * 4 + 3];

    const unsigned short* pv = vb16 + ((size_t)b * 128 + vh) * LLN + n;
    float* po = out + ((size_t)b * 512 + h * 128 + vh) * LLN + n;
#pragma unroll 4
    for (int v = 0; v < 64; v++) {
        const float* lrow = &lcsT[v][0];
        float4 c0 = *(const float4*)&lrow[0];
        float4 c1 = *(const float4*)&lrow[4];
        float4 c2 = *(const float4*)&lrow[8];
        float4 c3 = *(const float4*)&lrow[12];
        float lam = q4[0].x * c0.x + q4[0].y * c0.y + q4[0].z * c0.z + q4[0].w * c0.w
                  + q4[1].x * c1.x + q4[1].y * c1.y + q4[1].z * c1.z + q4[1].w * c1.w
                  + q4[2].x * c2.x + q4[2].y * c2.y + q4[2].z * c2.z + q4[2].w * c2.w
                  + q4[3].x * c3.x + q4[3].y * c3.y + q4[3].z * c3.z + q4[3].w * c3.w;
        float vvv = bf2f(pv[(size_t)v * LLN]);
        po[(size_t)v * LLN] = lam + s * vvv;
    }
}

extern "C" void kernel_launch(void* const* d_in, const int* in_sizes, int n_in,
                              void* d_out, int out_size, void* d_ws, size_t ws_size,
                              hipStream_t stream)
{
    const float* x   = (const float*)d_in[0];
    const float* Wq  = (const float*)d_in[1];
    const float* qg  = (const float*)d_in[2];
    const float* qb  = (const float*)d_in[3];
    const float* qm  = (const float*)d_in[4];
    const float* qv  = (const float*)d_in[5];
    const float* Wk  = (const float*)d_in[6];
    const float* Wv  = (const float*)d_in[7];
    const float* vg  = (const float*)d_in[8];
    const float* vb  = (const float*)d_in[9];
    const float* vm  = (const float*)d_in[10];
    const float* vva = (const float*)d_in[11];
    const float* emb = (const float*)d_in[12];
    float* out = (float*)d_out;

    float* kbuf = (float*)d_ws;                              // 16*16*2048 f32 (exp)
    float* lc2  = kbuf + (size_t)BB * 16 * LLN;              // 2*16*16*128 f32
    float* s2   = lc2 + (size_t)2 * BB * 16 * 128;           // 2*16*16 f32
    unsigned short* qb16 = (unsigned short*)(s2 + 512);      // 16*64*2048 u16
    unsigned short* vb16 = qb16 + (size_t)BB * 64 * LLN;     // 16*128*2048 u16
    unsigned short* Wpk  = vb16 + (size_t)BB * 128 * LLN;    // 64*6144 u16
    unsigned short* xpk  = Wpk + (size_t)64 * WIMG_U16;      // 256*2050*32 u16 (~33.6 MB)

    hipLaunchKernelGGL(prep_all, dim3(8, 16, 17), dim3(256), 0, stream,
                       x, Wq, Wk, Wv, xpk, Wpk);

    hipLaunchKernelGGL(conv_mfma, dim3(8, 4, 16), dim3(512), 0, stream,
                       xpk, Wpk, qg, qb, qm, qv, vg, vb, vm, vva,
                       qb16, kbuf, vb16);

    hipLaunchKernelGGL(lambdac_kernel, dim3(1024), dim3(256), 0, stream,
                       kbuf, vb16, lc2, s2);

    hipLaunchKernelGGL(final_kernel, dim3(32, 2, BB), dim3(256), 0, stream,
                       qb16, vb16, lc2, s2, emb, out);
}

// Round 10
// 190.212 us; speedup vs baseline: 1.0497x; 1.0031x over previous
//
#include <hip/hip_runtime.h>
#include <hip/hip_bf16.h>

#define BB 16
#define CIN 512
#define LLN 2048
#define EPSV 1e-5f
#define WIMG_U16 6144

typedef __attribute__((ext_vector_type(8))) short bf16x8s;
typedef __attribute__((ext_vector_type(4))) float f32x4;

__device__ __forceinline__ unsigned short f2bf(float f) {
    union { float f; unsigned int i; } c; c.f = f;
    unsigned int x = c.i;
    unsigned int lsb = (x >> 16) & 1;
    x += 0x7fff + lsb;            // RNE
    return (unsigned short)(x >> 16);
}
__device__ __forceinline__ float bf2f(unsigned short u) {
    union { unsigned int i; float f; } c; c.i = ((unsigned int)u) << 16; return c.f;
}
__device__ __forceinline__ float bflo(unsigned int w) {
    union { unsigned int i; float f; } c; c.i = w << 16; return c.f;
}
__device__ __forceinline__ float bfhi(unsigned int w) {
    union { unsigned int i; float f; } c; c.i = w & 0xffff0000u; return c.f;
}
// packed f32x2 -> bf16x2 (compiler emits v_cvt_pk_bf16_f32; RNE)
__device__ __forceinline__ unsigned int cvtpk2(float a, float b) {
    union { __hip_bfloat162 h; unsigned int u; } c;
    c.h = __float22bfloat162_rn(float2{a, b});
    return c.u;
}

// async global->LDS, 16B per lane, LDS dest = wave-uniform base + lane*16
__device__ __forceinline__ void g2l16(const void* g, void* l) {
    typedef const __attribute__((address_space(1))) unsigned int GU;
    typedef __attribute__((address_space(3))) unsigned int LU;
    __builtin_amdgcn_global_load_lds((GU*)g, (LU*)l, 16, 0, 0);
}

// ---------------- Kernel 0: weight repack only ----------------
// Wpk: [cot 4][chunk 16] images of [t 3][cf 4][lane 64][e 8] bf16 (frag-contig:
// in conv, ds_read_b128 at lane*16 gives each lane its MFMA A-fragment).
__global__ __launch_bounds__(256) void prep_w(
    const float* __restrict__ Wq, const float* __restrict__ Wk,
    const float* __restrict__ Wv, unsigned short* __restrict__ Wpk)
{
    const int tid = threadIdx.x;
    const int wblk = blockIdx.y * 8 + blockIdx.x;   // 0..127
    const int img = wblk >> 1, half = wblk & 1;     // img = cot*16 + chunk
    const int cot = img >> 4, chunk = img & 15;
    const int ci0 = chunk * 32;
    for (int i = half * 3072 + tid; i < half * 3072 + 3072; i += 256) {
        int t = i >> 11, r = i & 2047;
        int cf = r >> 9, lane = (r >> 3) & 63, e = i & 7;
        int lm = lane & 15, kq = lane >> 4;
        int cop = cot * 64 + cf * 16 + lm;
        int cig = ci0 + kq * 8 + e;
        float val = 0.f;
        if (cop < 64)        val = Wq[((size_t)cop * 512 + cig) * 3 + t];
        else if (cop < 80)   val = Wk[((size_t)(cop - 64) * 512 + cig) * 3 + t];
        else if (cop < 208)  val = Wv[((size_t)(cop - 80) * 512 + cig) * 3 + t];
        Wpk[(size_t)img * WIMG_U16 + i] = f2bf(val);
    }
}

// ---------------- Kernel 1: fused repack + MFMA conv + BN ----------------
// Block: 64 co x 256 n, 512 threads = 8 waves. Per 32-ci chunk:
//   (a) global_load_lds the fp32 slab [32ci][256n] -> 32 KB LDS scratch (linear,
//       coalesced; x is L3-resident so the 4x cot re-read is cache-served),
//   (b) transpose phase: column ds_read_b32 (2-way, free) -> v_cvt_pk_bf16_f32
//       -> swizzled ds_write_b128 into xT (same layout the MFMA B-read expects).
// xT single-buffered (16.5 KB), weights double-buffered (24.6 KB), scratch 32 KB
// -> 74.4 KB LDS = 2 blocks/CU, 16 waves/CU. Eliminates the xpk global image.
// q,v stored bf16; k stored exp(score-16) (softmax = ratio of sums downstream).
__global__ __launch_bounds__(512, 4) void conv_mfma(
    const float* __restrict__ x, const unsigned short* __restrict__ Wpk,
    const float* __restrict__ qg, const float* __restrict__ qb,
    const float* __restrict__ qm, const float* __restrict__ qv,
    const float* __restrict__ vg, const float* __restrict__ vb,
    const float* __restrict__ vm, const float* __restrict__ vvar,
    unsigned short* __restrict__ qb16, float* __restrict__ kbuf,
    unsigned short* __restrict__ vb16)
{
    __shared__ __align__(16) unsigned short xT[258 * 32];     // 16512 B
    __shared__ __align__(16) unsigned short wA[2][WIMG_U16];  // 24576 B
    __shared__ __align__(16) float xs32[32 * 256];            // 32768 B
    __shared__ float sscale[64], sshift[64];

    const int tid = threadIdx.x;
    const int wave = tid >> 6, lane = tid & 63;
    const int kq = lane >> 4, lm = lane & 15;
    const int n0 = blockIdx.x * 256;
    const int cot = blockIdx.y;          // 0..3 (64 co each)
    const int b = blockIdx.z;

    const float* xb = x + (size_t)b * CIN * LLN;
    const unsigned short* wbase = Wpk + (size_t)cot * 16 * WIMG_U16;

    float hl0 = 0.f, hl1 = 0.f;          // halo columns, reg-staged per chunk

#define STAGE_X32(chunk)                                                        \
    {                                                                           \
        const float* src = xb + (size_t)(chunk) * 32 * LLN + n0;                \
        _Pragma("unroll")                                                       \
        for (int j = 0; j < 4; j++) {                                           \
            int i = tid + j * 512;                                              \
            g2l16(src + (size_t)(i >> 6) * LLN + (i & 63) * 4,                  \
                  (char*)xs32 + (size_t)i * 16);                                \
        }                                                                       \
    }
#define STAGE_W(buf, chunk)                                                     \
    {                                                                           \
        const unsigned short* wsrc = wbase + (size_t)(chunk) * WIMG_U16;        \
        for (int i = tid; i < 768; i += 512)                                    \
            g2l16(wsrc + (size_t)i * 8, &wA[buf][i * 8]);                       \
    }
#define HALO_ISSUE(chunk)                                                       \
    if (tid < 32) {                                                             \
        int side = tid & 1, p = tid >> 1;                                       \
        int nh = side ? (n0 + 256) : (n0 - 1);                                  \
        hl0 = 0.f; hl1 = 0.f;                                                   \
        if (nh >= 0 && nh < LLN) {                                              \
            hl0 = xb[((size_t)(chunk) * 32 + 2 * p) * LLN + nh];                \
            hl1 = xb[((size_t)(chunk) * 32 + 2 * p + 1) * LLN + nh];            \
        }                                                                       \
    }
    // transpose+convert: thread -> row nl=tid>>1 (256 rows), half h=tid&1 owns
    // 16B groups {2h, 2h+1} (each = 8 ci). Write slot = group ^ ((rp>>1)&3).
#define TRANSPOSE()                                                             \
    {                                                                           \
        int nl = tid >> 1, h = tid & 1, rp = nl + 1;                            \
        int sig = (rp >> 1) & 3;                                                \
        unsigned short* row = &xT[rp * 32];                                     \
        _Pragma("unroll")                                                       \
        for (int g2 = 0; g2 < 2; g2++) {                                        \
            int gg = h * 2 + g2;                                                \
            float f0 = xs32[(gg * 8 + 0) * 256 + nl];                           \
            float f1 = xs32[(gg * 8 + 1) * 256 + nl];                           \
            float f2 = xs32[(gg * 8 + 2) * 256 + nl];                           \
            float f3 = xs32[(gg * 8 + 3) * 256 + nl];                           \
            float f4 = xs32[(gg * 8 + 4) * 256 + nl];                           \
            float f5 = xs32[(gg * 8 + 5) * 256 + nl];                           \
            float f6 = xs32[(gg * 8 + 6) * 256 + nl];                           \
            float f7 = xs32[(gg * 8 + 7) * 256 + nl];                           \
            uint4 w = make_uint4(cvtpk2(f0, f1), cvtpk2(f2, f3),                \
                                 cvtpk2(f4, f5), cvtpk2(f6, f7));               \
            *(uint4*)&row[(gg ^ sig) * 8] = w;                                  \
        }                                                                       \
        if (tid < 32) {                                                         \
            int side = tid & 1, p = tid >> 1;                                   \
            int hr = side ? 257 : 0;    /* sig==0 for both halo rows */         \
            *(unsigned int*)&xT[hr * 32 + p * 2] = cvtpk2(hl0, hl1);            \
        }                                                                       \
    }

    STAGE_X32(0) STAGE_W(0, 0) HALO_ISSUE(0)

    if (tid < 64) {                      // BN prep overlaps prologue loads
        int cop = cot * 64 + tid;
        float sc = 1.f, sh = 0.f;
        if (cop < 64) {
            float g = qg[cop], be = qb[cop], m = qm[cop], va = qv[cop];
            sc = g * rsqrtf(va + EPSV); sh = be - m * sc;
        } else if (cop >= 80 && cop < 208) {
            int cc = cop - 80;
            float g = vg[cc], be = vb[cc], m = vm[cc], va = vvar[cc];
            sc = g * rsqrtf(va + EPSV); sh = be - m * sc;
        }
        sscale[tid] = sc; sshift[tid] = sh;
    }

    f32x4 acc[4][2];
#pragma unroll
    for (int i = 0; i < 4; i++)
#pragma unroll
        for (int j = 0; j < 2; j++) acc[i][j] = (f32x4){0.f, 0.f, 0.f, 0.f};

    asm volatile("s_waitcnt vmcnt(0)" ::: "memory");
    __syncthreads();
    TRANSPOSE()
    __syncthreads();

    for (int chunk = 0; chunk < 16; chunk++) {
        const int cur = chunk & 1;
        // issue next chunk's staging (fp32 slab + weights + halo regs)
        if (chunk < 15) { STAGE_X32(chunk + 1) STAGE_W(cur ^ 1, chunk + 1) HALO_ISSUE(chunk + 1) }

        // MFMA phase on xT (chunk) + wA[cur]
#pragma unroll
        for (int t = 0; t < 3; t++) {
            bf16x8s aF[4];
#pragma unroll
            for (int cf = 0; cf < 4; cf++)
                aF[cf] = *(const bf16x8s*)&wA[cur][((t * 4 + cf) * 64 + lane) * 8];
#pragma unroll
            for (int fn = 0; fn < 2; fn++) {
                int lr = wave * 32 + fn * 16 + lm + t;
                int grp = kq ^ ((lr >> 1) & 3);       // matches TRANSPOSE swizzle
                bf16x8s bF = *(const bf16x8s*)&xT[lr * 32 + grp * 8];
#pragma unroll
                for (int cf = 0; cf < 4; cf++)
                    acc[cf][fn] = __builtin_amdgcn_mfma_f32_16x16x32_bf16(
                        aF[cf], bF, acc[cf][fn], 0, 0, 0);
            }
        }
        asm volatile("s_waitcnt vmcnt(0)" ::: "memory");
        __syncthreads();                 // slab landed; xT reads drained
        if (chunk < 15) { TRANSPOSE() __syncthreads(); }
    }
#undef STAGE_X32
#undef STAGE_W
#undef HALO_ISSUE
#undef TRANSPOSE

    // epilogue: C layout col=lane&15 (n), row=(lane>>4)*4+reg (co)
#pragma unroll
    for (int cf = 0; cf < 4; cf++) {
#pragma unroll
        for (int fn = 0; fn < 2; fn++) {
#pragma unroll
            for (int r = 0; r < 4; r++) {
                int col = cf * 16 + kq * 4 + r;        // co_local 0..63
                int cop = cot * 64 + col;
                if (cop >= 208) continue;
                float val = acc[cf][fn][r] * sscale[col] + sshift[col];
                int nout = n0 + wave * 32 + fn * 16 + lm;
                if (cop < 64)
                    qb16[((size_t)b * 64 + cop) * LLN + nout] = f2bf(val);
                else if (cop < 80)
                    kbuf[((size_t)b * 16 + (cop - 64)) * LLN + nout] = __expf(val - 16.f);
                else
                    vb16[((size_t)b * 128 + (cop - 80)) * LLN + nout] = f2bf(val);
            }
        }
    }
}

// ---------------- Kernel 2: lambda_c partials (n-split, no atomics) ---------
// kbuf holds exp(score-16). Each block reduces HALF the n-range:
//   lc2[half][b][k][v] = sum_{n in half} e[k][n]*v[v][n]
//   s2 [half][b][k]    = sum_{n in half} e[k][n]        (written by vg==0)
// final combines (l0+l1)/(s0+s1). grid 1024 = 4 blocks/CU.
__global__ __launch_bounds__(256) void lambdac_kernel(
    const float* __restrict__ kexp, const unsigned short* __restrict__ vb16,
    float* __restrict__ lc2, float* __restrict__ s2)
{
    const int wave = threadIdx.x >> 6;
    const int lane = threadIdx.x & 63;
    const int idx = blockIdx.x;          // 0..1023
    const int half = idx & 1;
    const int vgp = (idx >> 1) & 31;
    const int b = idx >> 6;
    const float* ps = kexp + ((size_t)b * 16 + wave * 4) * LLN + half * 1024;
    const unsigned short* pv = vb16 + ((size_t)b * 128 + vgp * 4) * LLN + half * 1024;

    float sum[4] = {0.f, 0.f, 0.f, 0.f};
    float acc[4][4];
#pragma unroll
    for (int k = 0; k < 4; k++)
#pragma unroll
        for (int v = 0; v < 4; v++) acc[k][v] = 0.f;
#pragma unroll
    for (int j = 0; j < 2; j++) {
        int n = (j * 64 + lane) * 8;
        float e[4][8];
#pragma unroll
        for (int k = 0; k < 4; k++) {
            float4 a = *(const float4*)&ps[(size_t)k * LLN + n];
            float4 c = *(const float4*)&ps[(size_t)k * LLN + n + 4];
            e[k][0] = a.x; e[k][1] = a.y; e[k][2] = a.z; e[k][3] = a.w;
            e[k][4] = c.x; e[k][5] = c.y; e[k][6] = c.z; e[k][7] = c.w;
            sum[k] += a.x + a.y + a.z + a.w + c.x + c.y + c.z + c.w;
        }
#pragma unroll
        for (int v = 0; v < 4; v++) {
            uint4 w = *(const uint4*)&pv[(size_t)v * LLN + n];
            float vv[8] = {bflo(w.x), bfhi(w.x), bflo(w.y), bfhi(w.y),
                           bflo(w.z), bfhi(w.z), bflo(w.w), bfhi(w.w)};
#pragma unroll
            for (int k = 0; k < 4; k++) {
                float t = 0.f;
#pragma unroll
                for (int q = 0; q < 8; q++) t += e[k][q] * vv[q];
                acc[k][v] += t;
            }
        }
    }
#pragma unroll
    for (int k = 0; k < 4; k++) {
#pragma unroll
        for (int off = 32; off > 0; off >>= 1)
            sum[k] += __shfl_xor(sum[k], off, 64);
#pragma unroll
        for (int v = 0; v < 4; v++)
#pragma unroll
            for (int off = 32; off > 0; off >>= 1)
                acc[k][v] += __shfl_xor(acc[k][v], off, 64);
    }
    if (lane == 0) {
#pragma unroll
        for (int k = 0; k < 4; k++) {
#pragma unroll
            for (int v = 0; v < 4; v++)
                lc2[(((size_t)half * 16 + b) * 16 + wave * 4 + k) * 128 + vgp * 4 + v]
                    = acc[k][v];
            if (vgp == 0)
                s2[((size_t)half * 16 + b) * 16 + wave * 4 + k] = sum[k];
        }
    }
}

// ---------------- Kernel 3: output, v-split for occupancy ----------------
// out[b][h*128+v][n] = sum_k q*lc[k][v] + (sum_k q*emb[k])*v[b][v][n]
// block = (n-tile 64, v-half, b) = 1024 blocks = 4/CU; wave = head.
// Combines lambda_c partials: lc = (l0+l1)/(s0+s1), folded into LDS fill.
__global__ __launch_bounds__(256) void final_kernel(
    const unsigned short* __restrict__ qb16, const unsigned short* __restrict__ vb16,
    const float* __restrict__ lc2, const float* __restrict__ s2,
    const float* __restrict__ emb, float* __restrict__ out)
{
    __shared__ float lcsT[64][16];    // row v_local, 16 k contiguous
    __shared__ float es[16], invd[16];
    const int tid = threadIdx.x;
    const int h = tid >> 6, nl = tid & 63;
    const int n0 = blockIdx.x * 64;   // 32 tiles
    const int vh = blockIdx.y * 64;   // v-half
    const int b = blockIdx.z;

    if (tid < 16) {
        es[tid] = emb[tid];
        invd[tid] = 1.f / (s2[(size_t)b * 16 + tid] + s2[256 + (size_t)b * 16 + tid]);
    }
    __syncthreads();
    for (int i = tid; i < 1024; i += 256) {
        int k = i & 15, vl = i >> 4;
        float l0 = lc2[((size_t)b * 16 + k) * 128 + vh + vl];
        float l1 = lc2[(size_t)32768 + ((size_t)b * 16 + k) * 128 + vh + vl];
        lcsT[vl][k] = (l0 + l1) * invd[k];
    }
    __syncthreads();

    const int n = n0 + nl;
    const unsigned short* pq = qb16 + ((size_t)b * 64 + h * 16) * LLN + n;
    float4 q4[4];
#pragma unroll
    for (int kk = 0; kk < 4; kk++) {
        q4[kk].x = bf2f(pq[(size_t)(kk * 4 + 0) * LLN]);
        q4[kk].y = bf2f(pq[(size_t)(kk * 4 + 1) * LLN]);
        q4[kk].z = bf2f(pq[(size_t)(kk * 4 + 2) * LLN]);
        q4[kk].w = bf2f(pq[(size_t)(kk * 4 + 3) * LLN]);
    }
    float s = 0.f;
#pragma unroll
    for (int kk = 0; kk < 4; kk++)
        s += q4[kk].x * es[kk * 4] + q4[kk].y * es[kk * 4 + 1]
           + q4[kk].z * es[kk * 4 + 2] + q4[kk].w * es[kk * 4 + 3];

    const unsigned short* pv = vb16 + ((size_t)b * 128 + vh) * LLN + n;
    float* po = out + ((size_t)b * 512 + h * 128 + vh) * LLN + n;
#pragma unroll 4
    for (int v = 0; v < 64; v++) {
        const float* lrow = &lcsT[v][0];
        float4 c0 = *(const float4*)&lrow[0];
        float4 c1 = *(const float4*)&lrow[4];
        float4 c2 = *(const float4*)&lrow[8];
        float4 c3 = *(const float4*)&lrow[12];
        float lam = q4[0].x * c0.x + q4[0].y * c0.y + q4[0].z * c0.z + q4[0].w * c0.w
                  + q4[1].x * c1.x + q4[1].y * c1.y + q4[1].z * c1.z + q4[1].w * c1.w
                  + q4[2].x * c2.x + q4[2].y * c2.y + q4[2].z * c2.z + q4[2].w * c2.w
                  + q4[3].x * c3.x + q4[3].y * c3.y + q4[3].z * c3.z + q4[3].w * c3.w;
        float vvv = bf2f(pv[(size_t)v * LLN]);
        po[(size_t)v * LLN] = lam + s * vvv;
    }
}

extern "C" void kernel_launch(void* const* d_in, const int* in_sizes, int n_in,
                              void* d_out, int out_size, void* d_ws, size_t ws_size,
                              hipStream_t stream)
{
    const float* x   = (const float*)d_in[0];
    const float* Wq  = (const float*)d_in[1];
    const float* qg  = (const float*)d_in[2];
    const float* qb  = (const float*)d_in[3];
    const float* qm  = (const float*)d_in[4];
    const float* qv  = (const float*)d_in[5];
    const float* Wk  = (const float*)d_in[6];
    const float* Wv  = (const float*)d_in[7];
    const float* vg  = (const float*)d_in[8];
    const float* vb  = (const float*)d_in[9];
    const float* vm  = (const float*)d_in[10];
    const float* vva = (const float*)d_in[11];
    const float* emb = (const float*)d_in[12];
    float* out = (float*)d_out;

    float* kbuf = (float*)d_ws;                              // 16*16*2048 f32 (exp)
    float* lc2  = kbuf + (size_t)BB * 16 * LLN;              // 2*16*16*128 f32
    float* s2   = lc2 + (size_t)2 * BB * 16 * 128;           // 2*16*16 f32
    unsigned short* qb16 = (unsigned short*)(s2 + 512);      // 16*64*2048 u16
    unsigned short* vb16 = qb16 + (size_t)BB * 64 * LLN;     // 16*128*2048 u16
    unsigned short* Wpk  = vb16 + (size_t)BB * 128 * LLN;    // 64*6144 u16

    hipLaunchKernelGGL(prep_w, dim3(8, 16), dim3(256), 0, stream, Wq, Wk, Wv, Wpk);

    hipLaunchKernelGGL(conv_mfma, dim3(8, 4, 16), dim3(512), 0, stream,
                       x, Wpk, qg, qb, qm, qv, vg, vb, vm, vva,
                       qb16, kbuf, vb16);

    hipLaunchKernelGGL(lambdac_kernel, dim3(1024), dim3(256), 0, stream,
                       kbuf, vb16, lc2, s2);

    hipLaunchKernelGGL(final_kernel, dim3(32, 2, BB), dim3(256), 0, stream,
                       qb16, vb16, lc2, s2, emb, out);
}